// Round 2
// baseline (1291.579 us; speedup 1.0000x reference)
//
#include <hip/hip_runtime.h>
#include <hip/hip_bf16.h>

#define N_NODES 50000
#define N_EDGES 1600000
#define E2 (N_EDGES + N_NODES)

static __device__ __forceinline__ float lrelu(float x) { return x > 0.f ? x : 0.2f * x; }

// ---------------- CSR build ----------------

__global__ void k_deg(const int* __restrict__ edst, int* __restrict__ deg) {
    int e = blockIdx.x * blockDim.x + threadIdx.x;
    if (e >= E2) return;
    int d = (e < N_EDGES) ? edst[e] : (e - N_EDGES);
    atomicAdd(&deg[d], 1);
}

__global__ void k_scan1(const int* __restrict__ deg, int* __restrict__ rowptr, int* __restrict__ bsum) {
    __shared__ int sd[256];
    int t = threadIdx.x;
    int i = blockIdx.x * 256 + t;
    int v = (i < N_NODES) ? deg[i] : 0;
    sd[t] = v;
    __syncthreads();
    for (int off = 1; off < 256; off <<= 1) {
        int add = (t >= off) ? sd[t - off] : 0;
        __syncthreads();
        sd[t] += add;
        __syncthreads();
    }
    if (i < N_NODES) rowptr[i + 1] = sd[t];
    if (t == 255) bsum[blockIdx.x] = sd[255];
}

__global__ void k_scan2(const int* __restrict__ bsum, int* __restrict__ boff, int nb) {
    __shared__ int sd[256];
    int t = threadIdx.x;
    sd[t] = (t < nb) ? bsum[t] : 0;
    __syncthreads();
    for (int off = 1; off < 256; off <<= 1) {
        int add = (t >= off) ? sd[t - off] : 0;
        __syncthreads();
        sd[t] += add;
        __syncthreads();
    }
    if (t < nb) boff[t] = (t > 0) ? sd[t - 1] : 0;
}

__global__ void k_scan3(int* __restrict__ rowptr, int* __restrict__ cursor, const int* __restrict__ boff) {
    int i = blockIdx.x * 256 + threadIdx.x;
    if (i < N_NODES) {
        int r = rowptr[i + 1] + boff[blockIdx.x];
        rowptr[i + 1] = r;
        cursor[i + 1] = r;
    }
    if (i == 0) { rowptr[0] = 0; cursor[0] = 0; }
}

__global__ void k_fill(const int* __restrict__ esrc, const int* __restrict__ edst,
                       int* __restrict__ cursor, int* __restrict__ col) {
    int e = blockIdx.x * blockDim.x + threadIdx.x;
    if (e >= E2) return;
    int s, d;
    if (e < N_EDGES) { s = esrc[e]; d = edst[e]; } else { s = d = e - N_EDGES; }
    int pos = atomicAdd(&cursor[d], 1);
    col[pos] = s;
}

// ---------------- layer-2 weight concat: Wc = [W2 | Wl] ----------------

__global__ void k_wcat(const float* __restrict__ W2, const float* __restrict__ Wl, float* __restrict__ Wc) {
    int i = blockIdx.x * 256 + threadIdx.x;  // 65536
    int k = i >> 8, j = i & 255;
    Wc[i] = (j < 128) ? W2[k * 128 + j] : Wl[k * 128 + (j - 128)];
}

// ---------------- fp32 SGEMM: C[M,N] = A[M,K] @ B[K,N], N=256, K=256 ----------------

__global__ __launch_bounds__(256) void k_sgemm(const float* __restrict__ A, const float* __restrict__ B,
                                               float* __restrict__ C, int M, int N, int K) {
    __shared__ float As[16][65];  // [k][m]
    __shared__ float Bs[16][64];  // [k][n]
    const int t = threadIdx.x;
    const int bm = blockIdx.x * 64, bn = blockIdx.y * 64;
    const int ar = t >> 2, ak = (t & 3) << 2;
    const int br = t >> 4, bc = (t & 15) << 2;
    const int tr = (t >> 4) << 2, tc = (t & 15) << 2;
    float acc[4][4] = {};
    int arow = bm + ar;
    if (arow >= M) arow = M - 1;
    const float* Aptr = A + (size_t)arow * K + ak;
    const float* Bptr = B + (size_t)br * N + bn + bc;
    for (int k0 = 0; k0 < K; k0 += 16) {
        float4 av = *(const float4*)(Aptr + k0);
        float4 bv = *(const float4*)(Bptr + (size_t)k0 * N);
        As[ak + 0][ar] = av.x; As[ak + 1][ar] = av.y; As[ak + 2][ar] = av.z; As[ak + 3][ar] = av.w;
        *(float4*)&Bs[br][bc] = bv;
        __syncthreads();
#pragma unroll
        for (int k = 0; k < 16; ++k) {
            float a0 = As[k][tr], a1 = As[k][tr + 1], a2 = As[k][tr + 2], a3 = As[k][tr + 3];
            float b0 = Bs[k][tc], b1 = Bs[k][tc + 1], b2 = Bs[k][tc + 2], b3 = Bs[k][tc + 3];
            acc[0][0] += a0 * b0; acc[0][1] += a0 * b1; acc[0][2] += a0 * b2; acc[0][3] += a0 * b3;
            acc[1][0] += a1 * b0; acc[1][1] += a1 * b1; acc[1][2] += a1 * b2; acc[1][3] += a1 * b3;
            acc[2][0] += a2 * b0; acc[2][1] += a2 * b1; acc[2][2] += a2 * b2; acc[2][3] += a2 * b3;
            acc[3][0] += a3 * b0; acc[3][1] += a3 * b1; acc[3][2] += a3 * b2; acc[3][3] += a3 * b3;
        }
        __syncthreads();
    }
#pragma unroll
    for (int i = 0; i < 4; ++i) {
        int row = bm + tr + i;
        if (row < M) {
            float4 v = make_float4(acc[i][0], acc[i][1], acc[i][2], acc[i][3]);
            *(float4*)&C[(size_t)row * N + bn + tc] = v;
        }
    }
}

// ---------------- attention logits: als/ald[n,h] = dot(P[n,h,:], a_s/a_d[h,:]) ----------------

template <int HEADS, int CHAN>
__global__ __launch_bounds__(64) void k_al(const float* __restrict__ P,
                                           const float* __restrict__ a_s, const float* __restrict__ a_d,
                                           float* __restrict__ als, float* __restrict__ ald) {
    int n = blockIdx.x;
    int l = threadIdx.x;
    const float* row = P + (size_t)n * 256;
#pragma unroll
    for (int h = 0; h < HEADS; ++h) {
        float ps = 0.f, pd = 0.f;
        for (int c = l; c < CHAN; c += 64) {
            float v = row[h * CHAN + c];
            ps += v * a_s[h * CHAN + c];
            pd += v * a_d[h * CHAN + c];
        }
#pragma unroll
        for (int off = 32; off > 0; off >>= 1) {
            ps += __shfl_xor(ps, off);
            pd += __shfl_xor(pd, off);
        }
        if (l == 0) { als[n * HEADS + h] = ps; ald[n * HEADS + h] = pd; }
    }
}

// ---------------- helpers ----------------

template <int HEADS>
__device__ __forceinline__ void load_als(const float* __restrict__ als, int src, float* v) {
    if constexpr (HEADS == 4) {
        float4 a = *(const float4*)(als + (size_t)src * 4);
        v[0] = a.x; v[1] = a.y; v[2] = a.z; v[3] = a.w;
    } else {
#pragma unroll
        for (int h = 0; h < HEADS; ++h) v[h] = als[(size_t)src * HEADS + h];
    }
}

// ---------------- attention softmax + aggregation (CSR, block per dst node) ----------------

template <int HEADS, int CHAN, bool RES, bool LIN>
__global__ __launch_bounds__(HEADS * CHAN) void k_agg(
    const float* __restrict__ P, const float* __restrict__ als, const float* __restrict__ ald,
    const int* __restrict__ rowptr, const int* __restrict__ col,
    const float* __restrict__ bias, const float* __restrict__ bias2,
    const float* __restrict__ resid, float* __restrict__ out) {
    constexpr int BLK = HEADS * CHAN;
    const int n = blockIdx.x;
    const int t = threadIdx.x;
    const int hd = t / CHAN;
    const int rs = rowptr[n];
    const int deg = rowptr[n + 1] - rs;

    __shared__ int s_src[BLK];
    __shared__ float s_w[BLK * HEADS];
    __shared__ float s_red[BLK * HEADS];

    float aldn[HEADS];
#pragma unroll
    for (int h = 0; h < HEADS; ++h) aldn[h] = ald[(size_t)n * HEADS + h];

    // phase 1: per-head max over neighborhood
    float lmax[HEADS];
#pragma unroll
    for (int h = 0; h < HEADS; ++h) lmax[h] = -3.402823466e38f;
    for (int j = t; j < deg; j += BLK) {
        int src = col[rs + j];
        float av[HEADS];
        load_als<HEADS>(als, src, av);
#pragma unroll
        for (int h = 0; h < HEADS; ++h) {
            float e = lrelu(av[h] + aldn[h]);
            lmax[h] = fmaxf(lmax[h], e);
        }
    }
#pragma unroll
    for (int h = 0; h < HEADS; ++h) s_red[t * HEADS + h] = lmax[h];
    __syncthreads();
    for (int s = BLK / 2; s > 0; s >>= 1) {
        if (t < s) {
#pragma unroll
            for (int h = 0; h < HEADS; ++h)
                s_red[t * HEADS + h] = fmaxf(s_red[t * HEADS + h], s_red[(t + s) * HEADS + h]);
        }
        __syncthreads();
    }
    float m[HEADS];
#pragma unroll
    for (int h = 0; h < HEADS; ++h) m[h] = s_red[h];
    __syncthreads();

    // phase 2: exp weights (LDS-staged per chunk) + weighted feature accumulation
    float acc = 0.f;
    float sw[HEADS];
#pragma unroll
    for (int h = 0; h < HEADS; ++h) sw[h] = 0.f;

    for (int base = 0; base < deg; base += BLK) {
        int j = base + t;
        if (j < deg) {
            int src = col[rs + j];
            s_src[t] = src;
            float av[HEADS];
            load_als<HEADS>(als, src, av);
#pragma unroll
            for (int h = 0; h < HEADS; ++h) {
                float e = lrelu(av[h] + aldn[h]);
                float wv = __expf(e - m[h]);
                s_w[t * HEADS + h] = wv;
                sw[h] += wv;
            }
        }
        __syncthreads();
        int cnt = min(BLK, deg - base);
        for (int jj = 0; jj < cnt; ++jj) {
            int src = s_src[jj];
            float wv = s_w[jj * HEADS + hd];
            acc += wv * P[(size_t)src * 256 + t];
        }
        __syncthreads();
    }

    // reduce sum of weights per head
#pragma unroll
    for (int h = 0; h < HEADS; ++h) s_red[t * HEADS + h] = sw[h];
    __syncthreads();
    for (int s = BLK / 2; s > 0; s >>= 1) {
        if (t < s) {
#pragma unroll
            for (int h = 0; h < HEADS; ++h)
                s_red[t * HEADS + h] += s_red[(t + s) * HEADS + h];
        }
        __syncthreads();
    }
    float stot = s_red[hd];

    float r = acc / stot + bias[t];
    if constexpr (RES) r += resid[(size_t)n * BLK + t];
    if constexpr (LIN) r += P[(size_t)n * 256 + BLK + t] + bias2[t];
    out[(size_t)n * BLK + t] = r;
}

// ---------------- launch ----------------

extern "C" void kernel_launch(void* const* d_in, const int* in_sizes, int n_in,
                              void* d_out, int out_size, void* d_ws, size_t ws_size,
                              hipStream_t stream) {
    const float* x   = (const float*)d_in[0];
    const int* ei    = (const int*)d_in[1];
    const int* esrc  = ei;
    const int* edst  = ei + N_EDGES;
    const float* W0  = (const float*)d_in[2];
    const float* as0 = (const float*)d_in[3];
    const float* ad0 = (const float*)d_in[4];
    const float* b0  = (const float*)d_in[5];
    const float* W1  = (const float*)d_in[6];
    const float* as1 = (const float*)d_in[7];
    const float* ad1 = (const float*)d_in[8];
    const float* b1  = (const float*)d_in[9];
    const float* W2  = (const float*)d_in[10];
    const float* as2 = (const float*)d_in[11];
    const float* ad2 = (const float*)d_in[12];
    const float* b2  = (const float*)d_in[13];
    const float* Wl  = (const float*)d_in[14];
    const float* bl  = (const float*)d_in[15];
    float* out = (float*)d_out;

    char* w = (char*)d_ws;
    auto alloc = [&](size_t bytes) { char* p = w; w += (bytes + 255) & ~(size_t)255; return p; };
    float* P   = (float*)alloc((size_t)N_NODES * 256 * 4);
    float* h0  = (float*)alloc((size_t)N_NODES * 256 * 4);
    float* h1  = (float*)alloc((size_t)N_NODES * 256 * 4);
    float* als = (float*)alloc((size_t)N_NODES * 4 * 4);
    float* ald = (float*)alloc((size_t)N_NODES * 4 * 4);
    float* Wc  = (float*)alloc(256 * 256 * 4);
    int* deg    = (int*)alloc((size_t)N_NODES * 4);
    int* rowptr = (int*)alloc((size_t)(N_NODES + 1) * 4);
    int* cursor = (int*)alloc((size_t)(N_NODES + 1) * 4);
    int* colb   = (int*)alloc((size_t)E2 * 4);
    int* bsum   = (int*)alloc(256 * 4);
    int* boff   = (int*)alloc(256 * 4);

    hipMemsetAsync(deg, 0, (size_t)N_NODES * 4, stream);

    int eb = (E2 + 255) / 256;
    int nb = (N_NODES + 255) / 256;
    k_deg<<<eb, 256, 0, stream>>>(edst, deg);
    k_scan1<<<nb, 256, 0, stream>>>(deg, rowptr, bsum);
    k_scan2<<<1, 256, 0, stream>>>(bsum, boff, nb);
    k_scan3<<<nb, 256, 0, stream>>>(rowptr, cursor, boff);
    k_fill<<<eb, 256, 0, stream>>>(esrc, edst, cursor, colb);
    k_wcat<<<256, 256, 0, stream>>>(W2, Wl, Wc);

    dim3 gg((N_NODES + 63) / 64, 4);
    // layer 0
    k_sgemm<<<gg, 256, 0, stream>>>(x, W0, P, N_NODES, 256, 256);
    k_al<4, 64><<<N_NODES, 64, 0, stream>>>(P, as0, ad0, als, ald);
    k_agg<4, 64, false, false><<<N_NODES, 256, 0, stream>>>(P, als, ald, rowptr, colb, b0, nullptr, nullptr, h0);
    // layer 1
    k_sgemm<<<gg, 256, 0, stream>>>(h0, W1, P, N_NODES, 256, 256);
    k_al<4, 64><<<N_NODES, 64, 0, stream>>>(P, as1, ad1, als, ald);
    k_agg<4, 64, true, false><<<N_NODES, 256, 0, stream>>>(P, als, ald, rowptr, colb, b1, nullptr, h0, h1);
    // layer 2 (combined GEMM: [P2 | h1@Wl])
    k_sgemm<<<gg, 256, 0, stream>>>(h1, Wc, P, N_NODES, 256, 256);
    k_al<1, 128><<<N_NODES, 64, 0, stream>>>(P, as2, ad2, als, ald);
    k_agg<1, 128, false, true><<<N_NODES, 128, 0, stream>>>(P, als, ald, rowptr, colb, b2, bl, nullptr, out);
}

// Round 3
// 954.973 us; speedup vs baseline: 1.3525x; 1.3525x over previous
//
#include <hip/hip_runtime.h>
#include <hip/hip_bf16.h>

#define N_NODES 50000
#define N_EDGES 1600000
#define E2 (N_EDGES + N_NODES)

typedef __attribute__((ext_vector_type(8))) short bf16x8;
typedef __attribute__((ext_vector_type(4))) float f32x4;

static __device__ __forceinline__ float lrelu(float x) { return x > 0.f ? x : 0.2f * x; }

static __device__ __forceinline__ float b2f(ushort u) {
    union { unsigned int u; float f; } v;
    v.u = ((unsigned int)u) << 16;
    return v.f;
}
static __device__ __forceinline__ ushort f2b(float f) {
    union { float f; unsigned int u; } v;
    v.f = f;
    unsigned int r = v.u + 0x7FFFu + ((v.u >> 16) & 1u);  // RNE
    return (ushort)(r >> 16);
}

// ---------------- CSR build ----------------

__global__ void k_deg(const int* __restrict__ edst, int* __restrict__ deg) {
    int e = blockIdx.x * blockDim.x + threadIdx.x;
    if (e >= E2) return;
    int d = (e < N_EDGES) ? edst[e] : (e - N_EDGES);
    atomicAdd(&deg[d], 1);
}

__global__ void k_scan1(const int* __restrict__ deg, int* __restrict__ rowptr, int* __restrict__ bsum) {
    __shared__ int sd[256];
    int t = threadIdx.x;
    int i = blockIdx.x * 256 + t;
    int v = (i < N_NODES) ? deg[i] : 0;
    sd[t] = v;
    __syncthreads();
    for (int off = 1; off < 256; off <<= 1) {
        int add = (t >= off) ? sd[t - off] : 0;
        __syncthreads();
        sd[t] += add;
        __syncthreads();
    }
    if (i < N_NODES) rowptr[i + 1] = sd[t];
    if (t == 255) bsum[blockIdx.x] = sd[255];
}

__global__ void k_scan2(const int* __restrict__ bsum, int* __restrict__ boff, int nb) {
    __shared__ int sd[256];
    int t = threadIdx.x;
    sd[t] = (t < nb) ? bsum[t] : 0;
    __syncthreads();
    for (int off = 1; off < 256; off <<= 1) {
        int add = (t >= off) ? sd[t - off] : 0;
        __syncthreads();
        sd[t] += add;
        __syncthreads();
    }
    if (t < nb) boff[t] = (t > 0) ? sd[t - 1] : 0;
}

__global__ void k_scan3(int* __restrict__ rowptr, int* __restrict__ cursor, const int* __restrict__ boff) {
    int i = blockIdx.x * 256 + threadIdx.x;
    if (i < N_NODES) {
        int r = rowptr[i + 1] + boff[blockIdx.x];
        rowptr[i + 1] = r;
        cursor[i + 1] = r;
    }
    if (i == 0) { rowptr[0] = 0; cursor[0] = 0; }
}

__global__ void k_fill(const int* __restrict__ esrc, const int* __restrict__ edst,
                       int* __restrict__ cursor, int* __restrict__ col) {
    int e = blockIdx.x * blockDim.x + threadIdx.x;
    if (e >= E2) return;
    int s, d;
    if (e < N_EDGES) { s = esrc[e]; d = edst[e]; } else { s = d = e - N_EDGES; }
    int pos = atomicAdd(&cursor[d], 1);
    col[pos] = s;
}

// ---------------- dtype prep ----------------

__global__ void k_quant(const float* __restrict__ x, ushort* __restrict__ xb, int n4) {
    int i = blockIdx.x * 256 + threadIdx.x;
    if (i >= n4) return;
    float4 v = ((const float4*)x)[i];
    ushort4 o;
    o.x = f2b(v.x); o.y = f2b(v.y); o.z = f2b(v.z); o.w = f2b(v.w);
    ((ushort4*)xb)[i] = o;
}

// W [256][256] fp32 row-major (k,n) -> Wt [n][k] bf16
__global__ void k_wt(const float* __restrict__ W, ushort* __restrict__ Wt) {
    int i = blockIdx.x * 256 + threadIdx.x;  // 65536
    int k = i >> 8, n = i & 255;
    Wt[n * 256 + k] = f2b(W[i]);
}

// Wc = [W2 | Wl] transposed to [n][k] bf16
__global__ void k_wtc(const float* __restrict__ W2, const float* __restrict__ Wl, ushort* __restrict__ Wt) {
    int i = blockIdx.x * 256 + threadIdx.x;  // 65536
    int k = i >> 8, n = i & 255;
    float v = (n < 128) ? W2[k * 128 + n] : Wl[k * 128 + (n - 128)];
    Wt[n * 256 + k] = f2b(v);
}

// ---------------- bf16 MFMA GEMM: C[M,256] = A[M,256] @ B[256,256] ----------------
// A bf16 row-major, Bt bf16 transposed [n][k]. Block = 4 waves, 32 rows, full N=256.
// MODE 0: write Cb (bf16) only. MODE 2: cols 0-127 -> Cb, cols 128-255 -> Pf compact [M][128] fp32.

template <int MODE>
__global__ __launch_bounds__(256) void k_mfma(const ushort* __restrict__ A, const ushort* __restrict__ Bt,
                                              float* __restrict__ Pf, ushort* __restrict__ Cb, int M) {
    const int t = threadIdx.x;
    const int w = t >> 6, l = t & 63;
    const int lr = l & 15, lk = l >> 4;
    const int m0 = blockIdx.x * 32;
    const int n0 = w * 64;
    f32x4 acc[2][4] = {};

    int r0 = m0 + lr;      if (r0 >= M) r0 = M - 1;
    int r1 = m0 + 16 + lr; if (r1 >= M) r1 = M - 1;
    const ushort* a0p = A + (size_t)r0 * 256 + lk * 8;
    const ushort* a1p = A + (size_t)r1 * 256 + lk * 8;
    const ushort* bp  = Bt + (size_t)(n0 + lr) * 256 + lk * 8;

#pragma unroll
    for (int k0 = 0; k0 < 256; k0 += 32) {
        bf16x8 a0 = *(const bf16x8*)(a0p + k0);
        bf16x8 a1 = *(const bf16x8*)(a1p + k0);
#pragma unroll
        for (int n = 0; n < 4; ++n) {
            bf16x8 b = *(const bf16x8*)(bp + n * 16 * 256 + k0);
            acc[0][n] = __builtin_amdgcn_mfma_f32_16x16x32_bf16(a0, b, acc[0][n], 0, 0, 0);
            acc[1][n] = __builtin_amdgcn_mfma_f32_16x16x32_bf16(a1, b, acc[1][n], 0, 0, 0);
        }
    }

    // C layout: col = lane&15 (+16n+n0), row = (lane>>4)*4 + reg (+16m+m0)   [m89-verified]
#pragma unroll
    for (int m = 0; m < 2; ++m) {
#pragma unroll
        for (int r = 0; r < 4; ++r) {
            int row = m0 + m * 16 + lk * 4 + r;
            if (row >= M) continue;
#pragma unroll
            for (int n = 0; n < 4; ++n) {
                int col = n0 + n * 16 + lr;
                float v = acc[m][n][r];
                if (MODE == 0) {
                    Cb[(size_t)row * 256 + col] = f2b(v);
                } else {
                    if (w < 2) Cb[(size_t)row * 256 + col] = f2b(v);
                    else       Pf[(size_t)row * 128 + (col - 128)] = v;
                }
            }
        }
    }
}

// ---------------- attention logits from bf16 features ----------------

template <int HEADS, int CHAN>
__global__ __launch_bounds__(256) void k_al(const ushort* __restrict__ Pb,
                                            const float* __restrict__ a_s, const float* __restrict__ a_d,
                                            float* __restrict__ als, float* __restrict__ ald) {
    int n = blockIdx.x * 4 + (threadIdx.x >> 6);
    if (n >= N_NODES) return;
    int l = threadIdx.x & 63;
    const ushort* row = Pb + (size_t)n * 256;
#pragma unroll
    for (int h = 0; h < HEADS; ++h) {
        float ps = 0.f, pd = 0.f;
#pragma unroll
        for (int c = l; c < CHAN; c += 64) {
            float v = b2f(row[h * CHAN + c]);
            ps += v * a_s[h * CHAN + c];
            pd += v * a_d[h * CHAN + c];
        }
#pragma unroll
        for (int off = 32; off > 0; off >>= 1) {
            ps += __shfl_xor(ps, off);
            pd += __shfl_xor(pd, off);
        }
        if (l == 0) { als[n * HEADS + h] = ps; ald[n * HEADS + h] = pd; }
    }
}

// ---------------- helpers ----------------

template <int HEADS>
__device__ __forceinline__ void load_als(const float* __restrict__ als, int src, float* v) {
    if constexpr (HEADS == 4) {
        float4 a = *(const float4*)(als + (size_t)src * 4);
        v[0] = a.x; v[1] = a.y; v[2] = a.z; v[3] = a.w;
    } else {
        v[0] = als[src];
    }
}

// ---------------- softmax + aggregation (block per dst node, bf16 gather) ----------------

template <int HEADS, int CHAN, bool RES, bool LIN, bool WRITEF, bool WRITEB>
__global__ __launch_bounds__(HEADS * CHAN) void k_agg(
    const ushort* __restrict__ Pb, const float* __restrict__ Pf,
    const float* __restrict__ als, const float* __restrict__ ald,
    const int* __restrict__ rowptr, const int* __restrict__ col,
    const float* __restrict__ bias, const float* __restrict__ bias2,
    const float* __restrict__ resid, float* __restrict__ out, ushort* __restrict__ outb) {
    constexpr int BLK = HEADS * CHAN;
    constexpr int NW = BLK / 64;
    const int n = blockIdx.x;
    const int t = threadIdx.x;
    const int hd = t / CHAN;
    const int rs = rowptr[n];
    const int deg = rowptr[n + 1] - rs;

    __shared__ int s_src[BLK];
    __shared__ float s_w[BLK * HEADS];
    __shared__ float s_m[HEADS];
    __shared__ float s_part[NW * HEADS];
    __shared__ float s_s[HEADS];

    float aldn[HEADS];
    load_als<HEADS>(ald, n, aldn);

    // phase A: wave 0 computes per-head max over neighborhood
    if (t < 64) {
        float mx[HEADS];
#pragma unroll
        for (int h = 0; h < HEADS; ++h) mx[h] = -3.402823466e38f;
        for (int j = t; j < deg; j += 64) {
            int src = col[rs + j];
            float av[HEADS];
            load_als<HEADS>(als, src, av);
#pragma unroll
            for (int h = 0; h < HEADS; ++h) mx[h] = fmaxf(mx[h], lrelu(av[h] + aldn[h]));
        }
#pragma unroll
        for (int off = 32; off > 0; off >>= 1)
#pragma unroll
            for (int h = 0; h < HEADS; ++h) mx[h] = fmaxf(mx[h], __shfl_xor(mx[h], off));
        if (t == 0)
#pragma unroll
            for (int h = 0; h < HEADS; ++h) s_m[h] = mx[h];
    }
    __syncthreads();
    float m[HEADS];
#pragma unroll
    for (int h = 0; h < HEADS; ++h) m[h] = s_m[h];

    // phase B: chunked weights + gather-accumulate
    float acc = 0.f;
    float sw[HEADS];
#pragma unroll
    for (int h = 0; h < HEADS; ++h) sw[h] = 0.f;

    for (int base = 0; base < deg; base += BLK) {
        int j = base + t;
        if (j < deg) {
            int src = col[rs + j];
            s_src[t] = src;
            float av[HEADS];
            load_als<HEADS>(als, src, av);
#pragma unroll
            for (int h = 0; h < HEADS; ++h) {
                float wv = __expf(lrelu(av[h] + aldn[h]) - m[h]);
                s_w[t * HEADS + h] = wv;
                sw[h] += wv;
            }
        }
        __syncthreads();
        int cnt = min(BLK, deg - base);
        for (int jj = 0; jj < cnt; ++jj) {
            float wv = s_w[jj * HEADS + hd];
            acc += wv * b2f(Pb[(size_t)s_src[jj] * 256 + t]);
        }
        __syncthreads();
    }

    // weight-sum: per-wave shuffle reduce, then combine
#pragma unroll
    for (int off = 32; off > 0; off >>= 1)
#pragma unroll
        for (int h = 0; h < HEADS; ++h) sw[h] += __shfl_xor(sw[h], off);
    if ((t & 63) == 0)
#pragma unroll
        for (int h = 0; h < HEADS; ++h) s_part[(t >> 6) * HEADS + h] = sw[h];
    __syncthreads();
    if (t < HEADS) {
        float s = 0.f;
#pragma unroll
        for (int wv = 0; wv < NW; ++wv) s += s_part[wv * HEADS + t];
        s_s[t] = s;
    }
    __syncthreads();
    float stot = s_s[hd];

    float r = acc / stot + bias[t];
    if constexpr (RES) r += resid[(size_t)n * BLK + t];
    if constexpr (LIN) r += Pf[(size_t)n * 128 + t] + bias2[t];
    if constexpr (WRITEF) out[(size_t)n * BLK + t] = r;
    if constexpr (WRITEB) outb[(size_t)n * BLK + t] = f2b(r);
}

// ---------------- launch ----------------

extern "C" void kernel_launch(void* const* d_in, const int* in_sizes, int n_in,
                              void* d_out, int out_size, void* d_ws, size_t ws_size,
                              hipStream_t stream) {
    const float* x   = (const float*)d_in[0];
    const int* ei    = (const int*)d_in[1];
    const int* esrc  = ei;
    const int* edst  = ei + N_EDGES;
    const float* W0  = (const float*)d_in[2];
    const float* as0 = (const float*)d_in[3];
    const float* ad0 = (const float*)d_in[4];
    const float* b0  = (const float*)d_in[5];
    const float* W1  = (const float*)d_in[6];
    const float* as1 = (const float*)d_in[7];
    const float* ad1 = (const float*)d_in[8];
    const float* b1  = (const float*)d_in[9];
    const float* W2  = (const float*)d_in[10];
    const float* as2 = (const float*)d_in[11];
    const float* ad2 = (const float*)d_in[12];
    const float* b2  = (const float*)d_in[13];
    const float* Wl  = (const float*)d_in[14];
    const float* bl  = (const float*)d_in[15];
    float* out = (float*)d_out;

    char* w = (char*)d_ws;
    auto alloc = [&](size_t bytes) { char* p = w; w += (bytes + 255) & ~(size_t)255; return p; };
    ushort* xb  = (ushort*)alloc((size_t)N_NODES * 256 * 2);  // also reused as h1b
    ushort* Pb  = (ushort*)alloc((size_t)N_NODES * 256 * 2);
    float*  h0  = (float*)alloc((size_t)N_NODES * 256 * 4);   // first half reused as Pf (50000*128 f32)
    ushort* h0b = (ushort*)alloc((size_t)N_NODES * 256 * 2);
    float* als = (float*)alloc((size_t)N_NODES * 4 * 4);
    float* ald = (float*)alloc((size_t)N_NODES * 4 * 4);
    ushort* Wt0 = (ushort*)alloc(256 * 256 * 2);
    ushort* Wt1 = (ushort*)alloc(256 * 256 * 2);
    ushort* Wtc = (ushort*)alloc(256 * 256 * 2);
    int* deg    = (int*)alloc((size_t)N_NODES * 4);
    int* rowptr = (int*)alloc((size_t)(N_NODES + 1) * 4);
    int* cursor = (int*)alloc((size_t)(N_NODES + 1) * 4);
    int* colb   = (int*)alloc((size_t)E2 * 4);
    int* bsum   = (int*)alloc(256 * 4);
    int* boff   = (int*)alloc(256 * 4);
    ushort* h1b = xb;       // xb dead after layer-0 GEMM
    float*  Pf  = h0;       // h0 dead after layer-1 agg (residual read)

    hipMemsetAsync(deg, 0, (size_t)N_NODES * 4, stream);

    int eb = (E2 + 255) / 256;
    int nb = (N_NODES + 255) / 256;
    k_deg<<<eb, 256, 0, stream>>>(edst, deg);
    k_scan1<<<nb, 256, 0, stream>>>(deg, rowptr, bsum);
    k_scan2<<<1, 256, 0, stream>>>(bsum, boff, nb);
    k_scan3<<<nb, 256, 0, stream>>>(rowptr, cursor, boff);
    k_fill<<<eb, 256, 0, stream>>>(esrc, edst, cursor, colb);

    k_quant<<<(N_NODES * 256 / 4 + 255) / 256, 256, 0, stream>>>(x, xb, N_NODES * 256 / 4);
    k_wt<<<256, 256, 0, stream>>>(W0, Wt0);
    k_wt<<<256, 256, 0, stream>>>(W1, Wt1);
    k_wtc<<<256, 256, 0, stream>>>(W2, Wl, Wtc);

    const int gm = (N_NODES + 31) / 32;
    const int ga = (N_NODES + 3) / 4;

    // layer 0
    k_mfma<0><<<gm, 256, 0, stream>>>(xb, Wt0, nullptr, Pb, N_NODES);
    k_al<4, 64><<<ga, 256, 0, stream>>>(Pb, as0, ad0, als, ald);
    k_agg<4, 64, false, false, true, true><<<N_NODES, 256, 0, stream>>>(
        Pb, nullptr, als, ald, rowptr, colb, b0, nullptr, nullptr, h0, h0b);
    // layer 1
    k_mfma<0><<<gm, 256, 0, stream>>>(h0b, Wt1, nullptr, Pb, N_NODES);
    k_al<4, 64><<<ga, 256, 0, stream>>>(Pb, as1, ad1, als, ald);
    k_agg<4, 64, true, false, false, true><<<N_NODES, 256, 0, stream>>>(
        Pb, nullptr, als, ald, rowptr, colb, b1, nullptr, h0, nullptr, h1b);
    // layer 2: GEMM computes [h1@W2 (bf16, cols 0-127) | h1@Wl (fp32 compact)]
    k_mfma<2><<<gm, 256, 0, stream>>>(h1b, Wtc, Pf, Pb, N_NODES);
    k_al<1, 128><<<ga, 256, 0, stream>>>(Pb, as2, ad2, als, ald);
    k_agg<1, 128, false, true, true, false><<<N_NODES, 128, 0, stream>>>(
        Pb, Pf, als, ald, rowptr, colb, b2, bl, nullptr, out, nullptr);
}

// Round 5
// 908.538 us; speedup vs baseline: 1.4216x; 1.0511x over previous
//
#include <hip/hip_runtime.h>
#include <hip/hip_bf16.h>

#define N_NODES 50000
#define N_EDGES 1600000
#define E2 (N_EDGES + N_NODES)

typedef __attribute__((ext_vector_type(8))) short bf16x8;
typedef __attribute__((ext_vector_type(4))) float f32x4;

static __device__ __forceinline__ float lrelu(float x) { return x > 0.f ? x : 0.2f * x; }

static __device__ __forceinline__ float b2f(ushort u) {
    union { unsigned int u; float f; } v;
    v.u = ((unsigned int)u) << 16;
    return v.f;
}
static __device__ __forceinline__ float hi2f(unsigned int u) {
    union { unsigned int u; float f; } v;
    v.u = u & 0xffff0000u;
    return v.f;
}
static __device__ __forceinline__ float lo2f(unsigned int u) {
    union { unsigned int u; float f; } v;
    v.u = u << 16;
    return v.f;
}
static __device__ __forceinline__ ushort f2b(float f) {
    union { float f; unsigned int u; } v;
    v.f = f;
    unsigned int r = v.u + 0x7FFFu + ((v.u >> 16) & 1u);  // RNE
    return (ushort)(r >> 16);
}

// ---------------- CSR build ----------------

__global__ void k_deg(const int* __restrict__ edst, int* __restrict__ deg) {
    int e = blockIdx.x * blockDim.x + threadIdx.x;
    if (e >= E2) return;
    int d = (e < N_EDGES) ? edst[e] : (e - N_EDGES);
    atomicAdd(&deg[d], 1);
}

__global__ void k_scan1(const int* __restrict__ deg, int* __restrict__ rowptr, int* __restrict__ bsum) {
    __shared__ int sd[256];
    int t = threadIdx.x;
    int i = blockIdx.x * 256 + t;
    int v = (i < N_NODES) ? deg[i] : 0;
    sd[t] = v;
    __syncthreads();
    for (int off = 1; off < 256; off <<= 1) {
        int add = (t >= off) ? sd[t - off] : 0;
        __syncthreads();
        sd[t] += add;
        __syncthreads();
    }
    if (i < N_NODES) rowptr[i + 1] = sd[t];
    if (t == 255) bsum[blockIdx.x] = sd[255];
}

__global__ void k_scan2(const int* __restrict__ bsum, int* __restrict__ boff, int nb) {
    __shared__ int sd[256];
    int t = threadIdx.x;
    sd[t] = (t < nb) ? bsum[t] : 0;
    __syncthreads();
    for (int off = 1; off < 256; off <<= 1) {
        int add = (t >= off) ? sd[t - off] : 0;
        __syncthreads();
        sd[t] += add;
        __syncthreads();
    }
    if (t < nb) boff[t] = (t > 0) ? sd[t - 1] : 0;
}

__global__ void k_scan3(int* __restrict__ rowptr, int* __restrict__ cursor, const int* __restrict__ boff) {
    int i = blockIdx.x * 256 + threadIdx.x;
    if (i < N_NODES) {
        int r = rowptr[i + 1] + boff[blockIdx.x];
        rowptr[i + 1] = r;
        cursor[i + 1] = r;
    }
    if (i == 0) { rowptr[0] = 0; cursor[0] = 0; }
}

__global__ void k_fill(const int* __restrict__ esrc, const int* __restrict__ edst,
                       int* __restrict__ cursor, int* __restrict__ col) {
    int e = blockIdx.x * blockDim.x + threadIdx.x;
    if (e >= E2) return;
    int s, d;
    if (e < N_EDGES) { s = esrc[e]; d = edst[e]; } else { s = d = e - N_EDGES; }
    int pos = atomicAdd(&cursor[d], 1);
    col[pos] = s;
}

// ---------------- dtype prep ----------------

__global__ void k_quant(const float* __restrict__ x, ushort* __restrict__ xb, int n4) {
    int i = blockIdx.x * 256 + threadIdx.x;
    if (i >= n4) return;
    float4 v = ((const float4*)x)[i];
    ushort4 o;
    o.x = f2b(v.x); o.y = f2b(v.y); o.z = f2b(v.z); o.w = f2b(v.w);
    ((ushort4*)xb)[i] = o;
}

// W [256][256] fp32 row-major (k,n) -> Wt [n][k] bf16
__global__ void k_wt(const float* __restrict__ W, ushort* __restrict__ Wt) {
    int i = blockIdx.x * 256 + threadIdx.x;  // 65536
    int k = i >> 8, n = i & 255;
    Wt[n * 256 + k] = f2b(W[i]);
}

// Wc = [W2 | Wl] transposed to [n][k] bf16
__global__ void k_wtc(const float* __restrict__ W2, const float* __restrict__ Wl, ushort* __restrict__ Wt) {
    int i = blockIdx.x * 256 + threadIdx.x;  // 65536
    int k = i >> 8, n = i & 255;
    float v = (n < 128) ? W2[k * 128 + n] : Wl[k * 128 + (n - 128)];
    Wt[n * 256 + k] = f2b(v);
}

// ---------------- bf16 MFMA GEMM: C[M,256] = A[M,256] @ B[256,256] ----------------

template <int MODE>
__global__ __launch_bounds__(256) void k_mfma(const ushort* __restrict__ A, const ushort* __restrict__ Bt,
                                              float* __restrict__ Pf, ushort* __restrict__ Cb, int M) {
    const int t = threadIdx.x;
    const int w = t >> 6, l = t & 63;
    const int lr = l & 15, lk = l >> 4;
    const int m0 = blockIdx.x * 32;
    const int n0 = w * 64;
    f32x4 acc[2][4] = {};

    int r0 = m0 + lr;      if (r0 >= M) r0 = M - 1;
    int r1 = m0 + 16 + lr; if (r1 >= M) r1 = M - 1;
    const ushort* a0p = A + (size_t)r0 * 256 + lk * 8;
    const ushort* a1p = A + (size_t)r1 * 256 + lk * 8;
    const ushort* bp  = Bt + (size_t)(n0 + lr) * 256 + lk * 8;

#pragma unroll
    for (int k0 = 0; k0 < 256; k0 += 32) {
        bf16x8 a0 = *(const bf16x8*)(a0p + k0);
        bf16x8 a1 = *(const bf16x8*)(a1p + k0);
#pragma unroll
        for (int n = 0; n < 4; ++n) {
            bf16x8 b = *(const bf16x8*)(bp + n * 16 * 256 + k0);
            acc[0][n] = __builtin_amdgcn_mfma_f32_16x16x32_bf16(a0, b, acc[0][n], 0, 0, 0);
            acc[1][n] = __builtin_amdgcn_mfma_f32_16x16x32_bf16(a1, b, acc[1][n], 0, 0, 0);
        }
    }

    // C layout: col = lane&15 (+16n+n0), row = (lane>>4)*4 + reg (+16m+m0)   [m89-verified]
#pragma unroll
    for (int m = 0; m < 2; ++m) {
#pragma unroll
        for (int r = 0; r < 4; ++r) {
            int row = m0 + m * 16 + lk * 4 + r;
            if (row >= M) continue;
#pragma unroll
            for (int n = 0; n < 4; ++n) {
                int col = n0 + n * 16 + lr;
                float v = acc[m][n][r];
                if (MODE == 0) {
                    Cb[(size_t)row * 256 + col] = f2b(v);
                } else {
                    if (w < 2) Cb[(size_t)row * 256 + col] = f2b(v);
                    else       Pf[(size_t)row * 128 + (col - 128)] = v;
                }
            }
        }
    }
}

// ---------------- attention logits from bf16 features ----------------

template <int HEADS, int CHAN>
__global__ __launch_bounds__(256) void k_al(const ushort* __restrict__ Pb,
                                            const float* __restrict__ a_s, const float* __restrict__ a_d,
                                            float* __restrict__ als, float* __restrict__ ald) {
    int n = blockIdx.x * 4 + (threadIdx.x >> 6);
    if (n >= N_NODES) return;
    int l = threadIdx.x & 63;
    const ushort* row = Pb + (size_t)n * 256;
#pragma unroll
    for (int h = 0; h < HEADS; ++h) {
        float ps = 0.f, pd = 0.f;
#pragma unroll
        for (int c = l; c < CHAN; c += 64) {
            float v = b2f(row[h * CHAN + c]);
            ps += v * a_s[h * CHAN + c];
            pd += v * a_d[h * CHAN + c];
        }
#pragma unroll
        for (int off = 32; off > 0; off >>= 1) {
            ps += __shfl_xor(ps, off);
            pd += __shfl_xor(pd, off);
        }
        if (l == 0) { als[n * HEADS + h] = ps; ald[n * HEADS + h] = pd; }
    }
}

// ---------------- helpers ----------------

template <int HEADS>
__device__ __forceinline__ void load_als(const float* __restrict__ als, int src, float* v) {
    if constexpr (HEADS == 4) {
        float4 a = *(const float4*)(als + (size_t)src * 4);
        v[0] = a.x; v[1] = a.y; v[2] = a.z; v[3] = a.w;
    } else {
        v[0] = als[src];
    }
}

// ---------------- softmax + aggregation: wave-per-neighbor vectorized gather ----------------
// No max subtraction (logits are O(1), exp in fp32 safe; softmax shift-invariant).
// Pb row stride is ALWAYS 256 (layer-2 features occupy cols 0-127 of the 256-wide buffer).

template <int HEADS, int CHAN, bool RES, bool LIN, bool WRITEF, bool WRITEB>
__global__ __launch_bounds__(HEADS * CHAN) void k_agg(
    const ushort* __restrict__ Pb, const float* __restrict__ Pf,
    const float* __restrict__ als, const float* __restrict__ ald,
    const int* __restrict__ rowptr, const int* __restrict__ col,
    const float* __restrict__ bias, const float* __restrict__ bias2,
    const float* __restrict__ resid, float* __restrict__ out, ushort* __restrict__ outb) {
    constexpr int BLK = HEADS * CHAN;   // == channel count == threads
    constexpr int NW = BLK / 64;        // waves per block
    constexpr int CPL = BLK / 64;       // channels per lane (4 or 2)
    const int n = blockIdx.x;
    const int t = threadIdx.x;
    const int w = t >> 6, l = t & 63;
    const int rs = rowptr[n];
    const int deg = rowptr[n + 1] - rs;

    __shared__ int s_src[BLK];
    __shared__ float s_w[BLK * HEADS];
    __shared__ float s_acc[NW * BLK];
    __shared__ float s_part[NW * HEADS];
    __shared__ float s_s[HEADS];

    float aldn[HEADS];
    load_als<HEADS>(ald, n, aldn);

    float acc[CPL];
#pragma unroll
    for (int c = 0; c < CPL; ++c) acc[c] = 0.f;
    float sw[HEADS];
#pragma unroll
    for (int h = 0; h < HEADS; ++h) sw[h] = 0.f;

    for (int base = 0; base < deg; base += BLK) {
        int j = base + t;
        if (j < deg) {
            int src = col[rs + j];
            s_src[t] = src;
            float av[HEADS];
            load_als<HEADS>(als, src, av);
#pragma unroll
            for (int h = 0; h < HEADS; ++h) {
                float wv = __expf(lrelu(av[h] + aldn[h]));
                s_w[t * HEADS + h] = wv;
                sw[h] += wv;
            }
        }
        __syncthreads();
        int cnt = min(BLK, deg - base);
        // wave w handles neighbors w, w+NW, ... ; lane loads CPL channels in one vector load
        for (int jj = w; jj < cnt; jj += NW) {
            int src = __builtin_amdgcn_readfirstlane(s_src[jj]);  // wave-uniform -> SGPR base
            if constexpr (CPL == 4) {
                float wv = s_w[jj * HEADS + (l >> 4)];  // head of channels 4l..4l+3
                uint2 v = *(const uint2*)(Pb + (size_t)src * 256 + l * 4);
                acc[0] += wv * lo2f(v.x);
                acc[1] += wv * hi2f(v.x);
                acc[2] += wv * lo2f(v.y);
                acc[3] += wv * hi2f(v.y);
            } else {
                float wv = s_w[jj * HEADS];  // single head
                unsigned int v = *(const unsigned int*)(Pb + (size_t)src * 256 + l * 2);  // stride 256!
                acc[0] += wv * lo2f(v);
                acc[1] += wv * hi2f(v);
            }
        }
        __syncthreads();
    }

    // weight-sum reduce: per-wave shuffle, then cross-wave
#pragma unroll
    for (int off = 32; off > 0; off >>= 1)
#pragma unroll
        for (int h = 0; h < HEADS; ++h) sw[h] += __shfl_xor(sw[h], off);
    if (l == 0)
#pragma unroll
        for (int h = 0; h < HEADS; ++h) s_part[w * HEADS + h] = sw[h];

    // stash per-wave partial feature sums
#pragma unroll
    for (int c = 0; c < CPL; ++c) s_acc[w * BLK + l * CPL + c] = acc[c];
    __syncthreads();

    if (t < HEADS) {
        float s = 0.f;
#pragma unroll
        for (int wv = 0; wv < NW; ++wv) s += s_part[wv * HEADS + t];
        s_s[t] = s;
    }
    __syncthreads();

    // final: thread t owns channel t
    float a = 0.f;
#pragma unroll
    for (int wv = 0; wv < NW; ++wv) a += s_acc[wv * BLK + t];
    float stot = s_s[t / CHAN];
    float r = a / stot + bias[t];
    if constexpr (RES) r += resid[(size_t)n * BLK + t];
    if constexpr (LIN) r += Pf[(size_t)n * 128 + t] + bias2[t];
    if constexpr (WRITEF) out[(size_t)n * BLK + t] = r;
    if constexpr (WRITEB) outb[(size_t)n * BLK + t] = f2b(r);
}

// ---------------- launch ----------------

extern "C" void kernel_launch(void* const* d_in, const int* in_sizes, int n_in,
                              void* d_out, int out_size, void* d_ws, size_t ws_size,
                              hipStream_t stream) {
    const float* x   = (const float*)d_in[0];
    const int* ei    = (const int*)d_in[1];
    const int* esrc  = ei;
    const int* edst  = ei + N_EDGES;
    const float* W0  = (const float*)d_in[2];
    const float* as0 = (const float*)d_in[3];
    const float* ad0 = (const float*)d_in[4];
    const float* b0  = (const float*)d_in[5];
    const float* W1  = (const float*)d_in[6];
    const float* as1 = (const float*)d_in[7];
    const float* ad1 = (const float*)d_in[8];
    const float* b1  = (const float*)d_in[9];
    const float* W2  = (const float*)d_in[10];
    const float* as2 = (const float*)d_in[11];
    const float* ad2 = (const float*)d_in[12];
    const float* b2  = (const float*)d_in[13];
    const float* Wl  = (const float*)d_in[14];
    const float* bl  = (const float*)d_in[15];
    float* out = (float*)d_out;

    char* w = (char*)d_ws;
    auto alloc = [&](size_t bytes) { char* p = w; w += (bytes + 255) & ~(size_t)255; return p; };
    ushort* xb  = (ushort*)alloc((size_t)N_NODES * 256 * 2);  // reused as h1b
    ushort* Pb  = (ushort*)alloc((size_t)N_NODES * 256 * 2);
    float*  h0  = (float*)alloc((size_t)N_NODES * 256 * 4);   // first half reused as Pf
    ushort* h0b = (ushort*)alloc((size_t)N_NODES * 256 * 2);
    float* als = (float*)alloc((size_t)N_NODES * 4 * 4);
    float* ald = (float*)alloc((size_t)N_NODES * 4 * 4);
    ushort* Wt0 = (ushort*)alloc(256 * 256 * 2);
    ushort* Wt1 = (ushort*)alloc(256 * 256 * 2);
    ushort* Wtc = (ushort*)alloc(256 * 256 * 2);
    int* deg    = (int*)alloc((size_t)N_NODES * 4);
    int* rowptr = (int*)alloc((size_t)(N_NODES + 1) * 4);
    int* cursor = (int*)alloc((size_t)(N_NODES + 1) * 4);
    int* colb   = (int*)alloc((size_t)E2 * 4);
    int* bsum   = (int*)alloc(256 * 4);
    int* boff   = (int*)alloc(256 * 4);
    ushort* h1b = xb;
    float*  Pf  = h0;

    hipMemsetAsync(deg, 0, (size_t)N_NODES * 4, stream);

    int eb = (E2 + 255) / 256;
    int nb = (N_NODES + 255) / 256;
    k_deg<<<eb, 256, 0, stream>>>(edst, deg);
    k_scan1<<<nb, 256, 0, stream>>>(deg, rowptr, bsum);
    k_scan2<<<1, 256, 0, stream>>>(bsum, boff, nb);
    k_scan3<<<nb, 256, 0, stream>>>(rowptr, cursor, boff);
    k_fill<<<eb, 256, 0, stream>>>(esrc, edst, cursor, colb);

    k_quant<<<(N_NODES * 256 / 4 + 255) / 256, 256, 0, stream>>>(x, xb, N_NODES * 256 / 4);
    k_wt<<<256, 256, 0, stream>>>(W0, Wt0);
    k_wt<<<256, 256, 0, stream>>>(W1, Wt1);
    k_wtc<<<256, 256, 0, stream>>>(W2, Wl, Wtc);

    const int gm = (N_NODES + 31) / 32;
    const int ga = (N_NODES + 3) / 4;

    // layer 0
    k_mfma<0><<<gm, 256, 0, stream>>>(xb, Wt0, nullptr, Pb, N_NODES);
    k_al<4, 64><<<ga, 256, 0, stream>>>(Pb, as0, ad0, als, ald);
    k_agg<4, 64, false, false, true, true><<<N_NODES, 256, 0, stream>>>(
        Pb, nullptr, als, ald, rowptr, colb, b0, nullptr, nullptr, h0, h0b);
    // layer 1
    k_mfma<0><<<gm, 256, 0, stream>>>(h0b, Wt1, nullptr, Pb, N_NODES);
    k_al<4, 64><<<ga, 256, 0, stream>>>(Pb, as1, ad1, als, ald);
    k_agg<4, 64, true, false, false, true><<<N_NODES, 256, 0, stream>>>(
        Pb, nullptr, als, ald, rowptr, colb, b1, nullptr, h0, nullptr, h1b);
    // layer 2: GEMM computes [h1@W2 (bf16, cols 0-127) | h1@Wl (fp32 compact)]
    k_mfma<2><<<gm, 256, 0, stream>>>(h1b, Wtc, Pf, Pb, N_NODES);
    k_al<1, 128><<<ga, 256, 0, stream>>>(Pb, as2, ad2, als, ald);
    k_agg<1, 128, false, true, true, false><<<N_NODES, 128, 0, stream>>>(
        Pb, Pf, als, ald, rowptr, colb, b2, bl, nullptr, out, nullptr);
}

// Round 6
// 779.688 us; speedup vs baseline: 1.6565x; 1.1653x over previous
//
#include <hip/hip_runtime.h>
#include <hip/hip_bf16.h>

#define N_NODES 50000
#define N_EDGES 1600000
#define E2 (N_EDGES + N_NODES)

typedef __attribute__((ext_vector_type(8))) short bf16x8;
typedef __attribute__((ext_vector_type(4))) float f32x4;

static __device__ __forceinline__ float lrelu(float x) { return x > 0.f ? x : 0.2f * x; }

static __device__ __forceinline__ float b2f(ushort u) {
    union { unsigned int u; float f; } v;
    v.u = ((unsigned int)u) << 16;
    return v.f;
}
static __device__ __forceinline__ float hi2f(unsigned int u) {
    union { unsigned int u; float f; } v;
    v.u = u & 0xffff0000u;
    return v.f;
}
static __device__ __forceinline__ float lo2f(unsigned int u) {
    union { unsigned int u; float f; } v;
    v.u = u << 16;
    return v.f;
}
static __device__ __forceinline__ ushort f2b(float f) {
    union { float f; unsigned int u; } v;
    v.f = f;
    unsigned int r = v.u + 0x7FFFu + ((v.u >> 16) & 1u);  // RNE
    return (ushort)(r >> 16);
}

// ---------------- CSR build ----------------

__global__ void k_deg(const int* __restrict__ edst, int* __restrict__ deg) {
    int e = blockIdx.x * blockDim.x + threadIdx.x;
    if (e >= E2) return;
    int d = (e < N_EDGES) ? edst[e] : (e - N_EDGES);
    atomicAdd(&deg[d], 1);
}

__global__ void k_scan1(const int* __restrict__ deg, int* __restrict__ rowptr, int* __restrict__ bsum) {
    __shared__ int sd[256];
    int t = threadIdx.x;
    int i = blockIdx.x * 256 + t;
    int v = (i < N_NODES) ? deg[i] : 0;
    sd[t] = v;
    __syncthreads();
    for (int off = 1; off < 256; off <<= 1) {
        int add = (t >= off) ? sd[t - off] : 0;
        __syncthreads();
        sd[t] += add;
        __syncthreads();
    }
    if (i < N_NODES) rowptr[i + 1] = sd[t];
    if (t == 255) bsum[blockIdx.x] = sd[255];
}

__global__ void k_scan2(const int* __restrict__ bsum, int* __restrict__ boff, int nb) {
    __shared__ int sd[256];
    int t = threadIdx.x;
    sd[t] = (t < nb) ? bsum[t] : 0;
    __syncthreads();
    for (int off = 1; off < 256; off <<= 1) {
        int add = (t >= off) ? sd[t - off] : 0;
        __syncthreads();
        sd[t] += add;
        __syncthreads();
    }
    if (t < nb) boff[t] = (t > 0) ? sd[t - 1] : 0;
}

__global__ void k_scan3(int* __restrict__ rowptr, int* __restrict__ cursor, const int* __restrict__ boff) {
    int i = blockIdx.x * 256 + threadIdx.x;
    if (i < N_NODES) {
        int r = rowptr[i + 1] + boff[blockIdx.x];
        rowptr[i + 1] = r;
        cursor[i + 1] = r;
    }
    if (i == 0) { rowptr[0] = 0; cursor[0] = 0; }
}

__global__ void k_fill(const int* __restrict__ esrc, const int* __restrict__ edst,
                       int* __restrict__ cursor, int* __restrict__ col) {
    int e = blockIdx.x * blockDim.x + threadIdx.x;
    if (e >= E2) return;
    int s, d;
    if (e < N_EDGES) { s = esrc[e]; d = edst[e]; } else { s = d = e - N_EDGES; }
    int pos = atomicAdd(&cursor[d], 1);
    col[pos] = s;
}

// ---------------- dtype prep ----------------

__global__ void k_quant(const float* __restrict__ x, ushort* __restrict__ xb, int n4) {
    int i = blockIdx.x * 256 + threadIdx.x;
    if (i >= n4) return;
    float4 v = ((const float4*)x)[i];
    ushort4 o;
    o.x = f2b(v.x); o.y = f2b(v.y); o.z = f2b(v.z); o.w = f2b(v.w);
    ((ushort4*)xb)[i] = o;
}

// W [256][256] fp32 row-major (k,n) -> Wt [n][k] bf16
__global__ void k_wt(const float* __restrict__ W, ushort* __restrict__ Wt) {
    int i = blockIdx.x * 256 + threadIdx.x;  // 65536
    int k = i >> 8, n = i & 255;
    Wt[n * 256 + k] = f2b(W[i]);
}

// Wc = [W2 | Wl] transposed to [n][k] bf16
__global__ void k_wtc(const float* __restrict__ W2, const float* __restrict__ Wl, ushort* __restrict__ Wt) {
    int i = blockIdx.x * 256 + threadIdx.x;  // 65536
    int k = i >> 8, n = i & 255;
    float v = (n < 128) ? W2[k * 128 + n] : Wl[k * 128 + (n - 128)];
    Wt[n * 256 + k] = f2b(v);
}

// ---------------- bf16 MFMA GEMM: C[M,256] = A[M,256] @ B[256,256] ----------------
// FUSE: wave w's 64 cols == head w -> compute als/ald in-register (layers 0/1).

template <bool FUSE>
__global__ __launch_bounds__(256) void k_mfma(const ushort* __restrict__ A, const ushort* __restrict__ Bt,
                                              ushort* __restrict__ Cb, int M,
                                              const float* __restrict__ a_s, const float* __restrict__ a_d,
                                              float* __restrict__ als, float* __restrict__ ald) {
    const int t = threadIdx.x;
    const int w = t >> 6, l = t & 63;
    const int lr = l & 15, lk = l >> 4;
    const int m0 = blockIdx.x * 32;
    const int n0 = w * 64;
    f32x4 acc[2][4] = {};

    int r0 = m0 + lr;      if (r0 >= M) r0 = M - 1;
    int r1 = m0 + 16 + lr; if (r1 >= M) r1 = M - 1;
    const ushort* a0p = A + (size_t)r0 * 256 + lk * 8;
    const ushort* a1p = A + (size_t)r1 * 256 + lk * 8;
    const ushort* bp  = Bt + (size_t)(n0 + lr) * 256 + lk * 8;

#pragma unroll
    for (int k0 = 0; k0 < 256; k0 += 32) {
        bf16x8 a0 = *(const bf16x8*)(a0p + k0);
        bf16x8 a1 = *(const bf16x8*)(a1p + k0);
#pragma unroll
        for (int n = 0; n < 4; ++n) {
            bf16x8 b = *(const bf16x8*)(bp + n * 16 * 256 + k0);
            acc[0][n] = __builtin_amdgcn_mfma_f32_16x16x32_bf16(a0, b, acc[0][n], 0, 0, 0);
            acc[1][n] = __builtin_amdgcn_mfma_f32_16x16x32_bf16(a1, b, acc[1][n], 0, 0, 0);
        }
    }

    // C layout: col = n0 + n*16 + lr, row = m0 + m*16 + lk*4 + r   [m89-verified]
#pragma unroll
    for (int m = 0; m < 2; ++m) {
#pragma unroll
        for (int r = 0; r < 4; ++r) {
            int row = m0 + m * 16 + lk * 4 + r;
            if (row >= M) continue;
#pragma unroll
            for (int n = 0; n < 4; ++n) {
                Cb[(size_t)row * 256 + n0 + n * 16 + lr] = f2b(acc[m][n][r]);
            }
        }
    }

    if constexpr (FUSE) {
        float asc[4], adc[4];
#pragma unroll
        for (int n = 0; n < 4; ++n) {
            int c = n0 + n * 16 + lr;
            asc[n] = a_s[c];
            adc[n] = a_d[c];
        }
#pragma unroll
        for (int m = 0; m < 2; ++m) {
#pragma unroll
            for (int r = 0; r < 4; ++r) {
                float pa = 0.f, pd = 0.f;
#pragma unroll
                for (int n = 0; n < 4; ++n) {
                    pa += acc[m][n][r] * asc[n];
                    pd += acc[m][n][r] * adc[n];
                }
#pragma unroll
                for (int off = 1; off < 16; off <<= 1) {
                    pa += __shfl_xor(pa, off);
                    pd += __shfl_xor(pd, off);
                }
                if (lr == 0) {
                    int row = m0 + m * 16 + lk * 4 + r;
                    if (row < M) {
                        als[row * 4 + w] = pa;
                        ald[row * 4 + w] = pd;
                    }
                }
            }
        }
    }
}

// ---------------- attention logits (layer 2 only: 1 head over cols 0..127) ----------------

template <int HEADS, int CHAN>
__global__ __launch_bounds__(256) void k_al(const ushort* __restrict__ Pb,
                                            const float* __restrict__ a_s, const float* __restrict__ a_d,
                                            float* __restrict__ als, float* __restrict__ ald) {
    int n = blockIdx.x * 4 + (threadIdx.x >> 6);
    if (n >= N_NODES) return;
    int l = threadIdx.x & 63;
    const ushort* row = Pb + (size_t)n * 256;
#pragma unroll
    for (int h = 0; h < HEADS; ++h) {
        float ps = 0.f, pd = 0.f;
#pragma unroll
        for (int c = l; c < CHAN; c += 64) {
            float v = b2f(row[h * CHAN + c]);
            ps += v * a_s[h * CHAN + c];
            pd += v * a_d[h * CHAN + c];
        }
#pragma unroll
        for (int off = 32; off > 0; off >>= 1) {
            ps += __shfl_xor(ps, off);
            pd += __shfl_xor(pd, off);
        }
        if (l == 0) { als[n * HEADS + h] = ps; ald[n * HEADS + h] = pd; }
    }
}

// ---------------- helpers ----------------

template <int HEADS>
__device__ __forceinline__ void load_als(const float* __restrict__ als, int src, float* v) {
    if constexpr (HEADS == 4) {
        float4 a = *(const float4*)(als + (size_t)src * 4);
        v[0] = a.x; v[1] = a.y; v[2] = a.z; v[3] = a.w;
    } else {
        v[0] = als[src];
    }
}

// ---------------- softmax + aggregation: one WAVE per dst node ----------------
// 4 nodes per 256-thread block; no barriers (wave-synchronous LDS staging);
// no max subtraction (logits O(1), softmax shift-invariant).
// Pb row stride is ALWAYS 256.

template <int HEADS, int CHAN, bool RESB, bool LIN, bool WRITEF, bool WRITEB>
__global__ __launch_bounds__(256) void k_aggw(
    const ushort* __restrict__ Pb,
    const float* __restrict__ als, const float* __restrict__ ald,
    const int* __restrict__ rowptr, const int* __restrict__ col,
    const float* __restrict__ bias, const float* __restrict__ bias2,
    const ushort* __restrict__ residb, float* __restrict__ out, ushort* __restrict__ outb) {
    constexpr int BLK = HEADS * CHAN;
    constexpr int CPL = BLK / 64;       // channels per lane: 4 (layers 0/1) or 2 (layer 2)
    const int t = threadIdx.x;
    const int w = t >> 6, l = t & 63;
    const int n = blockIdx.x * 4 + w;   // grid is exactly N/4
    const int rs = rowptr[n];
    const int deg = rowptr[n + 1] - rs;

    __shared__ int s_src[4][64];
    __shared__ float s_w[4][64 * HEADS];

    float aldn[HEADS];
    load_als<HEADS>(ald, n, aldn);

    float acc[CPL];
#pragma unroll
    for (int c = 0; c < CPL; ++c) acc[c] = 0.f;
    float sw[HEADS];
#pragma unroll
    for (int h = 0; h < HEADS; ++h) sw[h] = 0.f;

    const int hsel = l >> 4;  // head of this lane's channels (HEADS==4 case)

    for (int base = 0; base < deg; base += 64) {
        int j = base + l;
        if (j < deg) {
            int src = col[rs + j];
            s_src[w][l] = src;
            float av[HEADS];
            load_als<HEADS>(als, src, av);
#pragma unroll
            for (int h = 0; h < HEADS; ++h) {
                float wv = __expf(lrelu(av[h] + aldn[h]));
                s_w[w][l * HEADS + h] = wv;
                sw[h] += wv;
            }
        }
        int cnt = min(64, deg - base);
        int jj = 0;
        for (; jj + 2 <= cnt; jj += 2) {
            int s0 = __builtin_amdgcn_readfirstlane(s_src[w][jj]);
            int s1 = __builtin_amdgcn_readfirstlane(s_src[w][jj + 1]);
            if constexpr (CPL == 4) {
                float w0 = s_w[w][jj * HEADS + hsel];
                float w1 = s_w[w][(jj + 1) * HEADS + hsel];
                uint2 v0 = *(const uint2*)(Pb + (size_t)s0 * 256 + l * 4);
                uint2 v1 = *(const uint2*)(Pb + (size_t)s1 * 256 + l * 4);
                acc[0] += w0 * lo2f(v0.x); acc[1] += w0 * hi2f(v0.x);
                acc[2] += w0 * lo2f(v0.y); acc[3] += w0 * hi2f(v0.y);
                acc[0] += w1 * lo2f(v1.x); acc[1] += w1 * hi2f(v1.x);
                acc[2] += w1 * lo2f(v1.y); acc[3] += w1 * hi2f(v1.y);
            } else {
                float w0 = s_w[w][jj];
                float w1 = s_w[w][jj + 1];
                unsigned int v0 = *(const unsigned int*)(Pb + (size_t)s0 * 256 + l * 2);
                unsigned int v1 = *(const unsigned int*)(Pb + (size_t)s1 * 256 + l * 2);
                acc[0] += w0 * lo2f(v0); acc[1] += w0 * hi2f(v0);
                acc[0] += w1 * lo2f(v1); acc[1] += w1 * hi2f(v1);
            }
        }
        if (jj < cnt) {
            int s0 = __builtin_amdgcn_readfirstlane(s_src[w][jj]);
            if constexpr (CPL == 4) {
                float w0 = s_w[w][jj * HEADS + hsel];
                uint2 v0 = *(const uint2*)(Pb + (size_t)s0 * 256 + l * 4);
                acc[0] += w0 * lo2f(v0.x); acc[1] += w0 * hi2f(v0.x);
                acc[2] += w0 * lo2f(v0.y); acc[3] += w0 * hi2f(v0.y);
            } else {
                float w0 = s_w[w][jj];
                unsigned int v0 = *(const unsigned int*)(Pb + (size_t)s0 * 256 + l * 2);
                acc[0] += w0 * lo2f(v0); acc[1] += w0 * hi2f(v0);
            }
        }
    }

    // weight-sum: full-wave shuffle reduce
#pragma unroll
    for (int off = 32; off > 0; off >>= 1)
#pragma unroll
        for (int h = 0; h < HEADS; ++h) sw[h] += __shfl_xor(sw[h], off);

    float stot;
    if constexpr (HEADS == 4) {
        stot = (hsel == 0) ? sw[0] : (hsel == 1) ? sw[1] : (hsel == 2) ? sw[2] : sw[3];
    } else {
        stot = sw[0];
    }
    float rinv = 1.0f / stot;

    float r[CPL];
#pragma unroll
    for (int c = 0; c < CPL; ++c) r[c] = acc[c] * rinv + bias[l * CPL + c];
    if constexpr (RESB) {
        ushort4 rv = *(const ushort4*)(residb + (size_t)n * 256 + l * 4);
        r[0] += b2f(rv.x); r[1] += b2f(rv.y); r[2] += b2f(rv.z); r[3] += b2f(rv.w);
    }
    if constexpr (LIN) {
        unsigned int lv = *(const unsigned int*)(Pb + (size_t)n * 256 + 128 + l * 2);
        float2 bv = *(const float2*)(bias2 + l * 2);
        r[0] += lo2f(lv) + bv.x;
        r[1] += hi2f(lv) + bv.y;
    }
    if constexpr (WRITEF) {
        if constexpr (CPL == 4) {
            *(float4*)&out[(size_t)n * BLK + l * 4] = make_float4(r[0], r[1], r[2], r[3]);
        } else {
            *(float2*)&out[(size_t)n * BLK + l * 2] = make_float2(r[0], r[1]);
        }
    }
    if constexpr (WRITEB) {
        ushort4 o;
        o.x = f2b(r[0]); o.y = f2b(r[1]); o.z = f2b(r[2]); o.w = f2b(r[3]);
        *(ushort4*)&outb[(size_t)n * BLK + l * 4] = o;
    }
}

// ---------------- launch ----------------

extern "C" void kernel_launch(void* const* d_in, const int* in_sizes, int n_in,
                              void* d_out, int out_size, void* d_ws, size_t ws_size,
                              hipStream_t stream) {
    const float* x   = (const float*)d_in[0];
    const int* ei    = (const int*)d_in[1];
    const int* esrc  = ei;
    const int* edst  = ei + N_EDGES;
    const float* W0  = (const float*)d_in[2];
    const float* as0 = (const float*)d_in[3];
    const float* ad0 = (const float*)d_in[4];
    const float* b0  = (const float*)d_in[5];
    const float* W1  = (const float*)d_in[6];
    const float* as1 = (const float*)d_in[7];
    const float* ad1 = (const float*)d_in[8];
    const float* b1  = (const float*)d_in[9];
    const float* W2  = (const float*)d_in[10];
    const float* as2 = (const float*)d_in[11];
    const float* ad2 = (const float*)d_in[12];
    const float* b2  = (const float*)d_in[13];
    const float* Wl  = (const float*)d_in[14];
    const float* bl  = (const float*)d_in[15];
    float* out = (float*)d_out;

    char* w = (char*)d_ws;
    auto alloc = [&](size_t bytes) { char* p = w; w += (bytes + 255) & ~(size_t)255; return p; };
    ushort* xb  = (ushort*)alloc((size_t)N_NODES * 256 * 2);  // reused as h1b
    ushort* Pb  = (ushort*)alloc((size_t)N_NODES * 256 * 2);
    ushort* h0b = (ushort*)alloc((size_t)N_NODES * 256 * 2);
    float* als = (float*)alloc((size_t)N_NODES * 4 * 4);
    float* ald = (float*)alloc((size_t)N_NODES * 4 * 4);
    ushort* Wt0 = (ushort*)alloc(256 * 256 * 2);
    ushort* Wt1 = (ushort*)alloc(256 * 256 * 2);
    ushort* Wtc = (ushort*)alloc(256 * 256 * 2);
    int* deg    = (int*)alloc((size_t)N_NODES * 4);
    int* rowptr = (int*)alloc((size_t)(N_NODES + 1) * 4);
    int* cursor = (int*)alloc((size_t)(N_NODES + 1) * 4);
    int* colb   = (int*)alloc((size_t)E2 * 4);
    int* bsum   = (int*)alloc(256 * 4);
    int* boff   = (int*)alloc(256 * 4);
    ushort* h1b = xb;

    hipMemsetAsync(deg, 0, (size_t)N_NODES * 4, stream);

    int eb = (E2 + 255) / 256;
    int nb = (N_NODES + 255) / 256;
    k_deg<<<eb, 256, 0, stream>>>(edst, deg);
    k_scan1<<<nb, 256, 0, stream>>>(deg, rowptr, bsum);
    k_scan2<<<1, 256, 0, stream>>>(bsum, boff, nb);
    k_scan3<<<nb, 256, 0, stream>>>(rowptr, cursor, boff);
    k_fill<<<eb, 256, 0, stream>>>(esrc, edst, cursor, colb);

    k_quant<<<(N_NODES * 256 / 4 + 255) / 256, 256, 0, stream>>>(x, xb, N_NODES * 256 / 4);
    k_wt<<<256, 256, 0, stream>>>(W0, Wt0);
    k_wt<<<256, 256, 0, stream>>>(W1, Wt1);
    k_wtc<<<256, 256, 0, stream>>>(W2, Wl, Wtc);

    const int gm = (N_NODES + 31) / 32;
    const int ga = (N_NODES + 3) / 4;
    const int gn = N_NODES / 4;  // 12500 exact

    // layer 0 (GEMM + fused attention logits)
    k_mfma<true><<<gm, 256, 0, stream>>>(xb, Wt0, Pb, N_NODES, as0, ad0, als, ald);
    k_aggw<4, 64, false, false, false, true><<<gn, 256, 0, stream>>>(
        Pb, als, ald, rowptr, colb, b0, nullptr, nullptr, nullptr, h0b);
    // layer 1
    k_mfma<true><<<gm, 256, 0, stream>>>(h0b, Wt1, Pb, N_NODES, as1, ad1, als, ald);
    k_aggw<4, 64, true, false, false, true><<<gn, 256, 0, stream>>>(
        Pb, als, ald, rowptr, colb, b1, nullptr, h0b, nullptr, h1b);
    // layer 2: GEMM -> [h1@W2 | h1@Wl] all bf16 in Pb
    k_mfma<false><<<gm, 256, 0, stream>>>(h1b, Wtc, Pb, N_NODES, nullptr, nullptr, nullptr, nullptr);
    k_al<1, 128><<<ga, 256, 0, stream>>>(Pb, as2, ad2, als, ald);
    k_aggw<1, 128, false, true, true, false><<<gn, 256, 0, stream>>>(
        Pb, als, ald, rowptr, colb, b2, bl, nullptr, out, nullptr);
}